// Round 12
// baseline (224.716 us; speedup 1.0000x reference)
//
#include <hip/hip_runtime.h>
#include <math.h>
#include <stdint.h>

#define DDIM   256
#define HWSZ   1024
#define NROWS  32768
#define KCODES 1024
#define BN     64
#define BK     128
#define BD     32
#define NT     256
#define WSP    132
#define TAU    4.0e-4f      // flag gap threshold (3-term err ~1e-5 + grid 3e-5)
#define VEPS   2.0e-3f      // verify threshold (layout errors are O(0.1))

// ws layout (byte offsets)
#define WS_WNORM 0                       // float[1024]           (4 KB)
#define WS_KEYS  4096                    // u64[32768]            (256 KB)
#define WS_FLAGS 266240                  // int[32768]            (128 KB)
#define WS_WHI   397312                  // bf16 hi planes        (512 KB)
#define WS_WLO   921600                  // bf16 lo planes        (512 KB)
#define WS_NEED_MFMA 1445888
#define WS_NEED_F32  266240

typedef __attribute__((ext_vector_type(8)))  short short8;
typedef __attribute__((ext_vector_type(16))) float f32x16;

__device__ __forceinline__ uint32_t fbits(float f) { return __float_as_uint(f); }
__device__ __forceinline__ float    ubits(uint32_t u) { return __uint_as_float(u); }
__device__ __forceinline__ uint32_t bf16rne(float f) {
  uint32_t u = fbits(f);
  return (u + 0x7FFFu + ((u >> 16) & 1u)) >> 16;
}
__device__ __forceinline__ uint32_t flipbits(float d) {
  uint32_t b = fbits(d);
  return (b & 0x80000000u) ? ~b : (b | 0x80000000u);
}
__device__ __forceinline__ float unflip(uint32_t x) {
  return ubits((x & 0x80000000u) ? (x & 0x7FFFFFFFu) : ~x);
}
__device__ __forceinline__ unsigned long long umin64(unsigned long long a, unsigned long long b) { return a < b ? a : b; }
__device__ __forceinline__ unsigned long long umax64(unsigned long long a, unsigned long long b) { return a > b ? a : b; }

// ---------------------------------------------------------------------------
// k1: per-code squared norms + zero the loss slot (proven, verbatim)
// ---------------------------------------------------------------------------
__global__ __launch_bounds__(256)
void vq_wnorm(const float* __restrict__ weight, float* __restrict__ wnorm,
              float* __restrict__ loss_slot) {
  const int tid  = threadIdx.x;
  const int lane = tid & 63;
  const int code = blockIdx.x * 4 + (tid >> 6);
  float4 v = *(const float4*)(weight + (size_t)code * DDIM + lane * 4);
  float s = v.x * v.x + v.y * v.y + v.z * v.z + v.w * v.w;
#pragma unroll
  for (int off = 1; off < 64; off <<= 1) s += __shfl_xor(s, off);
  if (lane == 0) wnorm[code] = s;
  if (blockIdx.x == 0 && tid == 0) *loss_slot = 0.0f;
}

// ---------------------------------------------------------------------------
// k1b: codebook -> bf16 hi/lo planes (proven layout, verbatim)
// plane per 16-dim chunk: [2 oct][1024 code][8 bf16] = 32 KB
// ---------------------------------------------------------------------------
__global__ __launch_bounds__(256)
void vq_prep(const float* __restrict__ weight, char* __restrict__ ws) {
  const int t    = threadIdx.x;
  const int code = blockIdx.x * 8 + (t >> 5);
  const int l32  = t & 31;
  const int d0   = l32 * 8;
  const int ch   = l32 >> 1;
  const int slot = l32 & 1;
  const float* wr = weight + (size_t)code * DDIM + d0;
  float4 f0 = *(const float4*)(wr);
  float4 f1 = *(const float4*)(wr + 4);
  float x[8] = {f0.x, f0.y, f0.z, f0.w, f1.x, f1.y, f1.z, f1.w};
  uint32_t hp[4], lp[4];
#pragma unroll
  for (int j = 0; j < 4; ++j) {
    float a = x[2*j], b = x[2*j+1];
    uint32_t ha = bf16rne(a), hb = bf16rne(b);
    float la = a - ubits(ha << 16);
    float lb = b - ubits(hb << 16);
    hp[j] = ha | (hb << 16);
    lp[j] = bf16rne(la) | (bf16rne(lb) << 16);
  }
  const size_t off = (size_t)ch * 32768 + (size_t)slot * 16384 + (size_t)code * 16;
  *(uint4*)(ws + WS_WHI + off) = make_uint4(hp[0], hp[1], hp[2], hp[3]);
  *(uint4*)(ws + WS_WLO + off) = make_uint4(lp[0], lp[1], lp[2], lp[3]);
}

// ---------------------------------------------------------------------------
// k2: 3-term split-bf16 MFMA argmin, barrier-free main loop with EXPLICIT
// depth-1 register double-buffer of the B stream (static names, no copies):
// chunk ch+1's 8 loads fly while chunk ch's 12 MFMAs execute (counted vmcnt).
// Fused gather/transpose/loss epilogue. Verify + gap-flag kept verbatim.
// ---------------------------------------------------------------------------
__global__ __launch_bounds__(512)
void vq_mfma3(const float* __restrict__ latent, const float* __restrict__ weight,
              char* __restrict__ ws, float* __restrict__ out) {
  __shared__ __align__(16) short AH[16][2][32][8];  // 16 KB [ch][oct][row][8]
  __shared__ __align__(16) short AL[16][2][32][8];  // 16 KB
  __shared__ ulonglong2 cand[32][8];                // 4 KB
  __shared__ unsigned long long sM1[32];
  __shared__ int sGap[32];
  __shared__ int sVer[8];
  __shared__ float sRed[8];

  const int tid  = threadIdx.x;
  const int l    = tid & 63;
  const int w    = tid >> 6;
  const int ln31 = l & 31;
  const int half = l >> 5;
  const int b    = blockIdx.x >> 5;
  const int hw0  = (blockIdx.x & 31) * 32;
  const float* lat_b = latent + (size_t)b * (DDIM * HWSZ);
  const char* whi = ws + WS_WHI;
  const char* wlo = ws + WS_WLO;
  const float* wnorm = (const float*)(ws + WS_WNORM);

  f32x16 acc[4];
#pragma unroll
  for (int cg = 0; cg < 4; ++cg) acc[cg] = (f32x16)0.0f;

  // ---- stage ALL of A once: thread (arow, adim) covers 16 chunks ----
  {
    const int arow = tid & 31;
    const int adim = tid >> 5;          // 0..15
#pragma unroll 4
    for (int ch = 0; ch < 16; ++ch) {
      float x = lat_b[(size_t)(ch * 16 + adim) * HWSZ + hw0 + arow];
      uint32_t h = bf16rne(x);
      float lo = x - ubits(h << 16);
      AH[ch][adim >> 3][arow][adim & 7] = (short)h;
      AL[ch][adim >> 3][arow][adim & 7] = (short)bf16rne(lo);
    }
  }
  __syncthreads();   // the ONLY barrier before the fold

  // ---- per-wave B base pointers (code = w*128 + cg*32 + ln31) ----
  const char* whiw = whi + (size_t)half * 16384 + (size_t)(w * 128 + ln31) * 16;
  const char* wlow = wlo + (size_t)half * 16384 + (size_t)(w * 128 + ln31) * 16;

#define LDB8(H0,H1,H2,H3,L0,L1,L2,L3,CH) do {            \
    const size_t o_ = (size_t)(CH) * 32768;              \
    H0 = *(const short8*)(whiw + o_);                    \
    H1 = *(const short8*)(whiw + o_ + 512);              \
    H2 = *(const short8*)(whiw + o_ + 1024);             \
    H3 = *(const short8*)(whiw + o_ + 1536);             \
    L0 = *(const short8*)(wlow + o_);                    \
    L1 = *(const short8*)(wlow + o_ + 512);              \
    L2 = *(const short8*)(wlow + o_ + 1024);             \
    L3 = *(const short8*)(wlow + o_ + 1536);             \
  } while (0)

#define MBODY(CH,H0,H1,H2,H3,L0,L1,L2,L3) do {                               \
    short8 ah_ = *(const short8*)&AH[CH][half][ln31][0];                     \
    short8 al_ = *(const short8*)&AL[CH][half][ln31][0];                     \
    acc[0] = __builtin_amdgcn_mfma_f32_32x32x16_bf16(ah_, H0, acc[0], 0,0,0);\
    acc[1] = __builtin_amdgcn_mfma_f32_32x32x16_bf16(ah_, H1, acc[1], 0,0,0);\
    acc[2] = __builtin_amdgcn_mfma_f32_32x32x16_bf16(ah_, H2, acc[2], 0,0,0);\
    acc[3] = __builtin_amdgcn_mfma_f32_32x32x16_bf16(ah_, H3, acc[3], 0,0,0);\
    acc[0] = __builtin_amdgcn_mfma_f32_32x32x16_bf16(al_, H0, acc[0], 0,0,0);\
    acc[1] = __builtin_amdgcn_mfma_f32_32x32x16_bf16(al_, H1, acc[1], 0,0,0);\
    acc[2] = __builtin_amdgcn_mfma_f32_32x32x16_bf16(al_, H2, acc[2], 0,0,0);\
    acc[3] = __builtin_amdgcn_mfma_f32_32x32x16_bf16(al_, H3, acc[3], 0,0,0);\
    acc[0] = __builtin_amdgcn_mfma_f32_32x32x16_bf16(ah_, L0, acc[0], 0,0,0);\
    acc[1] = __builtin_amdgcn_mfma_f32_32x32x16_bf16(ah_, L1, acc[1], 0,0,0);\
    acc[2] = __builtin_amdgcn_mfma_f32_32x32x16_bf16(ah_, L2, acc[2], 0,0,0);\
    acc[3] = __builtin_amdgcn_mfma_f32_32x32x16_bf16(ah_, L3, acc[3], 0,0,0);\
  } while (0)

  {
    short8 eh0, eh1, eh2, eh3, el0, el1, el2, el3;   // even-chunk buffers
    short8 oh0, oh1, oh2, oh3, ol0, ol1, ol2, ol3;   // odd-chunk buffers
    LDB8(eh0, eh1, eh2, eh3, el0, el1, el2, el3, 0);
#pragma unroll 1
    for (int ch = 0; ch < 16; ch += 2) {
      LDB8(oh0, oh1, oh2, oh3, ol0, ol1, ol2, ol3, ch + 1);   // prefetch odd
      __builtin_amdgcn_s_setprio(1);
      MBODY(ch, eh0, eh1, eh2, eh3, el0, el1, el2, el3);
      __builtin_amdgcn_s_setprio(0);
      if (ch + 2 < 16)
        LDB8(eh0, eh1, eh2, eh3, el0, el1, el2, el3, ch + 2); // prefetch even
      __builtin_amdgcn_s_setprio(1);
      MBODY(ch + 1, oh0, oh1, oh2, oh3, ol0, ol1, ol2, ol3);
      __builtin_amdgcn_s_setprio(0);
    }
  }
#undef LDB8
#undef MBODY

  // ---- fold: per-row best/second-best over this wave's 128 codes ----
  float wnv[4];
#pragma unroll
  for (int cg = 0; cg < 4; ++cg) wnv[cg] = wnorm[w * 128 + cg * 32 + ln31];

#pragma unroll
  for (int reg = 0; reg < 16; ++reg) {
    unsigned long long kk[4];
#pragma unroll
    for (int cg = 0; cg < 4; ++cg) {
      const int code = w * 128 + cg * 32 + ln31;
      float dk = fmaf(-2.0f, acc[cg][reg], wnv[cg]);   // xn dropped: gap-flag covers
      kk[cg] = (((unsigned long long)flipbits(dk)) << 32) | (unsigned long long)(uint32_t)code;
    }
    unsigned long long a = umin64(kk[0], kk[1]), bb = umax64(kk[0], kk[1]);
    unsigned long long c = umin64(kk[2], kk[3]), e  = umax64(kk[2], kk[3]);
    unsigned long long m1 = umin64(a, c);
    unsigned long long m2 = umin64(umin64(bb, e), umax64(a, c));
#pragma unroll
    for (int s = 1; s <= 16; s <<= 1) {
      unsigned long long om1 = __shfl_xor(m1, s);
      unsigned long long om2 = __shfl_xor(m2, s);
      unsigned long long nm2 = umin64(umin64(m2, om2), umax64(m1, om1));
      m1 = umin64(m1, om1);
      m2 = nm2;
    }
    if (ln31 == 0) {
      const int row = (reg & 3) + 8 * (reg >> 2) + 4 * half;   // verified C/D map
      cand[row][w] = make_ulonglong2(m1, m2);
    }
  }
  __syncthreads();

  // ---- merge across waves; keys plain store (single writer per row) ----
  unsigned long long* keys = (unsigned long long*)(ws + WS_KEYS);
  if (tid < 256) {
    const int row = tid >> 3, ww = tid & 7;
    ulonglong2 cc = cand[row][ww];
    unsigned long long m1 = cc.x, m2 = cc.y;
#pragma unroll
    for (int s = 1; s <= 4; s <<= 1) {
      unsigned long long om1 = __shfl_xor(m1, s);
      unsigned long long om2 = __shfl_xor(m2, s);
      unsigned long long nm2 = umin64(umin64(m2, om2), umax64(m1, om1));
      m1 = umin64(m1, om1);
      m2 = nm2;
    }
    if (ww == 0) {
      keys[blockIdx.x * 32 + row] = m1;
      float d1 = unflip((uint32_t)(m1 >> 32));
      float d2 = unflip((uint32_t)(m2 >> 32));
      sGap[row] = (d2 - d1 < TAU) ? 1 : 0;
      sM1[row]  = m1;
    }
  }
  __syncthreads();

  // ---- verify all 32 rows: exact f32 check of each claimed winner ----
  {
    int bad = 0;
#pragma unroll
    for (int i = 0; i < 4; ++i) {
      const int row = w * 4 + i;
      unsigned long long m1 = sM1[row];
      const int c = (int)(m1 & 0x3FFull);
      float d1 = unflip((uint32_t)(m1 >> 32));
      float4 wv = *(const float4*)(weight + (size_t)c * DDIM + l * 4);
      float x0 = lat_b[(size_t)(4 * l + 0) * HWSZ + hw0 + row];
      float x1 = lat_b[(size_t)(4 * l + 1) * HWSZ + hw0 + row];
      float x2 = lat_b[(size_t)(4 * l + 2) * HWSZ + hw0 + row];
      float x3 = lat_b[(size_t)(4 * l + 3) * HWSZ + hw0 + row];
      float p = x0 * wv.x + x1 * wv.y + x2 * wv.z + x3 * wv.w;
#pragma unroll
      for (int s = 1; s < 64; s <<= 1) p += __shfl_xor(p, s);
      float dex = wnorm[c] - 2.0f * p;
      bad |= (fabsf(dex - d1) > VEPS) ? 1 : 0;
    }
    if (l == 0) sVer[w] = bad;
  }
  __syncthreads();
  if (tid == 0) {
    int vb = 0;
#pragma unroll
    for (int i = 0; i < 8; ++i) vb |= sVer[i];
    sVer[0] = vb;
  }
  __syncthreads();
  if (tid < 32)
    ((int*)(ws + WS_FLAGS))[blockIdx.x * 32 + tid] = sGap[tid] | sVer[0];

  // ---- fused epilogue: gather codes, transposed write, commitment loss ----
  {
    const int er = tid & 31;
    const int eg = tid >> 5;
    const int ec = (int)(sM1[er] & 0x3FFull);
    const float* wrow = weight + (size_t)ec * DDIM;
    float* out_b = out + (size_t)b * (DDIM * HWSZ);
    float ls = 0.f;
#pragma unroll
    for (int i = 0; i < 16; ++i) {
      const int d = i * 16 + eg;
      const size_t off = (size_t)d * HWSZ + hw0 + er;
      float x  = lat_b[off];
      float qv = wrow[d];
      out_b[off] = qv;
      float e = qv - x;
      ls += e * e;
    }
#pragma unroll
    for (int s = 1; s < 64; s <<= 1) ls += __shfl_xor(ls, s);
    if (l == 0) sRed[w] = ls;
  }
  __syncthreads();
  if (tid == 0) {
    float t = 0.f;
#pragma unroll
    for (int i = 0; i < 8; ++i) t += sRed[i];
    atomicAdd(out + (size_t)NROWS * DDIM, t * (1.0f / 8388608.0f));
  }
}

// ---------------------------------------------------------------------------
// k2b: exact coarse-grid re-argmin for flagged rows (round-6 math verbatim);
// rewrites the output row and patches the loss delta.
// ---------------------------------------------------------------------------
__global__ __launch_bounds__(256)
void vq_fixc(const float* __restrict__ latent, const float* __restrict__ weight,
             char* __restrict__ ws, float* __restrict__ out) {
  __shared__ float xs[256];
  __shared__ float bd[4];
  __shared__ int   bix[4];
  __shared__ int   sNew;
  __shared__ float sDl[4];
  const int t = threadIdx.x;
  const int* flags = (const int*)(ws + WS_FLAGS);
  const float* wnorm = (const float*)(ws + WS_WNORM);
  const unsigned long long* keys = (const unsigned long long*)(ws + WS_KEYS);

  for (int rloc = 0; rloc < 64; ++rloc) {
    const int grow = blockIdx.x * 64 + rloc;
    if (!flags[grow]) continue;                      // uniform per block
    const int b = grow >> 10, hw = grow & 1023;
    __syncthreads();
    xs[t] = latent[(size_t)b * (DDIM * HWSZ) + (size_t)t * HWSZ + hw];
    __syncthreads();
    float xnv = 0.f;
    const float4* x4 = (const float4*)xs;
#pragma unroll 16
    for (int k = 0; k < 64; ++k) {
      float4 xq = x4[k];
      xnv += xq.x * xq.x; xnv += xq.y * xq.y;
      xnv += xq.z * xq.z; xnv += xq.w * xq.w;
    }
    float best = INFINITY; int bi = 0;
    for (int j = 0; j < 4; ++j) {
      const int c = 256 * j + t;
      const float4* w4 = (const float4*)(weight + (size_t)c * DDIM);
      float dot = 0.f;
#pragma unroll 16
      for (int k = 0; k < 64; ++k) {
        float4 wv = w4[k];
        dot = fmaf(xs[4*k  ], wv.x, dot);
        dot = fmaf(xs[4*k+1], wv.y, dot);
        dot = fmaf(xs[4*k+2], wv.z, dot);
        dot = fmaf(xs[4*k+3], wv.w, dot);
      }
      float dist = (xnv + wnorm[c]) - 2.0f * dot;    // coarse grid, verbatim
      if (dist < best || (dist == best && c < bi)) { best = dist; bi = c; }
    }
#pragma unroll
    for (int s = 1; s <= 32; s <<= 1) {
      float od = __shfl_xor(best, s);
      int   oi = __shfl_xor(bi, s);
      if (od < best || (od == best && oi < bi)) { best = od; bi = oi; }
    }
    if ((t & 63) == 0) { bd[t >> 6] = best; bix[t >> 6] = bi; }
    __syncthreads();
    if (t == 0) {
      float fb = bd[0]; int fbi = bix[0];
#pragma unroll
      for (int ww = 1; ww < 4; ++ww)
        if (bd[ww] < fb || (bd[ww] == fb && bix[ww] < fbi)) { fb = bd[ww]; fbi = bix[ww]; }
      sNew = fbi;
    }
    __syncthreads();
    const int newc = sNew;
    const int oldc = (int)(keys[grow] & 0x3FFull);
    const float x  = xs[t];
    const float qn = weight[(size_t)newc * DDIM + t];
    const float qo = weight[(size_t)oldc * DDIM + t];
    out[(size_t)b * (DDIM * HWSZ) + (size_t)t * HWSZ + hw] = qn;
    float dl = (qn - x) * (qn - x) - (qo - x) * (qo - x);
#pragma unroll
    for (int s = 1; s < 64; s <<= 1) dl += __shfl_xor(dl, s);
    if ((t & 63) == 0) sDl[t >> 6] = dl;
    __syncthreads();
    if (t == 0)
      atomicAdd(out + (size_t)NROWS * DDIM,
                (sDl[0] + sDl[1] + sDl[2] + sDl[3]) * (1.0f / 8388608.0f));
    __syncthreads();
  }
}

// ---------------------------------------------------------------------------
// Fallback tier 1: round-6 proven f32 kernel (verbatim)
// ---------------------------------------------------------------------------
__global__ __launch_bounds__(NT, 4)
void vq_dist(const float* __restrict__ latent, const float* __restrict__ weight,
             const float* __restrict__ wnorm,
             unsigned long long* __restrict__ keys) {
  __shared__ __align__(16) float As[BD][BN];
  __shared__ __align__(16) float Ws[BD][WSP];

  const int tid = threadIdx.x;
  const int tx  = tid & 15;
  const int ty  = tid >> 4;
  const int rb  = blockIdx.x >> 2;
  const int q   = blockIdx.x & 3;
  const int b   = rb >> 4;
  const int hw0 = (rb & 15) * BN;
  const float* lat_b = latent + (size_t)b * DDIM * HWSZ;

  float xn[4] = {0.f, 0.f, 0.f, 0.f};
  for (int dc = 0; dc < DDIM / BD; ++dc) {
    __syncthreads();
#pragma unroll
    for (int i = 0; i < 2; ++i) {
      int idx = tid + i * NT;
      int dd = idx >> 4, f4 = idx & 15;
      *(float4*)&As[dd][f4 * 4] =
          *(const float4*)(lat_b + (size_t)(dc * BD + dd) * HWSZ + hw0 + f4 * 4);
    }
    __syncthreads();
#pragma unroll 8
    for (int dd = 0; dd < BD; ++dd) {
      float4 a = *(const float4*)&As[dd][ty * 4];
      xn[0] += a.x * a.x; xn[1] += a.y * a.y;
      xn[2] += a.z * a.z; xn[3] += a.w * a.w;
    }
  }

  float best[4] = {INFINITY, INFINITY, INFINITY, INFINITY};
  int   bidx[4] = {0, 0, 0, 0};

  for (int kt = 0; kt < 2; ++kt) {
    const int k0 = q * 256 + kt * BK;
    float acc[4][8];
#pragma unroll
    for (int r = 0; r < 4; ++r)
#pragma unroll
      for (int c = 0; c < 8; ++c) acc[r][c] = 0.f;

    for (int dc = 0; dc < DDIM / BD; ++dc) {
      const int d0 = dc * BD;
      __syncthreads();
#pragma unroll
      for (int i = 0; i < 2; ++i) {
        int idx = tid + i * NT;
        int dd = idx >> 4, f4 = idx & 15;
        *(float4*)&As[dd][f4 * 4] =
            *(const float4*)(lat_b + (size_t)(d0 + dd) * HWSZ + hw0 + f4 * 4);
      }
#pragma unroll
      for (int i = 0; i < 4; ++i) {
        int idx = tid + i * NT;
        int kl = idx >> 3, df = idx & 7;
        float4 v = *(const float4*)(weight + (size_t)(k0 + kl) * DDIM + d0 + df * 4);
        Ws[df * 4 + 0][kl] = v.x;
        Ws[df * 4 + 1][kl] = v.y;
        Ws[df * 4 + 2][kl] = v.z;
        Ws[df * 4 + 3][kl] = v.w;
      }
      __syncthreads();

#pragma unroll 8
      for (int dd = 0; dd < BD; ++dd) {
        float4 a  = *(const float4*)&As[dd][ty * 4];
        float4 w0 = *(const float4*)&Ws[dd][tx * 4];
        float4 w1 = *(const float4*)&Ws[dd][64 + tx * 4];
        float av[4] = {a.x, a.y, a.z, a.w};
        float wv[8] = {w0.x, w0.y, w0.z, w0.w, w1.x, w1.y, w1.z, w1.w};
#pragma unroll
        for (int r = 0; r < 4; ++r)
#pragma unroll
          for (int c = 0; c < 8; ++c)
            acc[r][c] += av[r] * wv[c];
      }
    }

#pragma unroll
    for (int c = 0; c < 8; ++c) {
      const int kg = k0 + ((c < 4) ? (tx * 4 + c) : (64 + tx * 4 + (c - 4)));
      const float wn = wnorm[kg];
#pragma unroll
      for (int r = 0; r < 4; ++r) {
        float dist = (xn[r] + wn) - 2.0f * acc[r][c];
        if (dist < best[r] || (dist == best[r] && kg < bidx[r])) {
          best[r] = dist; bidx[r] = kg;
        }
      }
    }
  }

#pragma unroll
  for (int j = 0; j < 4; ++j) {
    float bd = best[j];
    int   bi = bidx[j];
#pragma unroll
    for (int off = 1; off < 16; off <<= 1) {
      float od = __shfl_xor(bd, off);
      int   oi = __shfl_xor(bi, off);
      if (od < bd || (od == bd && oi < bi)) { bd = od; bi = oi; }
    }
    if (tx == 0) {
      unsigned long long key =
          (((unsigned long long)flipbits(bd)) << 32) | (unsigned long long)(uint32_t)bi;
      atomicMin(&keys[rb * 64 + ty * 4 + j], key);
    }
  }
}

// ---------------------------------------------------------------------------
// Fallback tier 1 epilogue (proven vq_emit)
// ---------------------------------------------------------------------------
__global__ __launch_bounds__(256)
void vq_emit(const float* __restrict__ latent, const float* __restrict__ weight,
             const unsigned long long* __restrict__ keys, float* __restrict__ out) {
  __shared__ int   sIdx[64];
  __shared__ float sRed[4];
  const int t   = threadIdx.x;
  const int blk = blockIdx.x;
  const int b   = blk >> 4;
  const int hw0 = (blk & 15) * 64;
  if (t < 64) sIdx[t] = (int)(keys[blk * 64 + t] & 0x3FFull);
  __syncthreads();

  const int hw4  = (t & 15) * 4;
  const int dgrp = t >> 4;
  const float* lat_b = latent + (size_t)b * DDIM * HWSZ;
  float* out_b = out + (size_t)b * DDIM * HWSZ;
  const float* w0 = weight + (size_t)sIdx[hw4 + 0] * DDIM;
  const float* w1 = weight + (size_t)sIdx[hw4 + 1] * DDIM;
  const float* w2 = weight + (size_t)sIdx[hw4 + 2] * DDIM;
  const float* w3 = weight + (size_t)sIdx[hw4 + 3] * DDIM;
  float lsum = 0.f;
#pragma unroll
  for (int it = 0; it < 16; ++it) {
    const int d = it * 16 + dgrp;
    float4 xv = *(const float4*)(lat_b + (size_t)d * HWSZ + hw0 + hw4);
    float q0 = w0[d], q1 = w1[d], q2 = w2[d], q3 = w3[d];
    *(float4*)(out_b + (size_t)d * HWSZ + hw0 + hw4) = make_float4(q0, q1, q2, q3);
    float e0 = q0 - xv.x, e1 = q1 - xv.y, e2 = q2 - xv.z, e3 = q3 - xv.w;
    lsum += e0 * e0 + e1 * e1 + e2 * e2 + e3 * e3;
  }
#pragma unroll
  for (int s = 1; s < 64; s <<= 1) lsum += __shfl_xor(lsum, s);
  if ((t & 63) == 0) sRed[t >> 6] = lsum;
  __syncthreads();
  if (t == 0) {
    float tot = sRed[0] + sRed[1] + sRed[2] + sRed[3];
    atomicAdd(out + (size_t)NROWS * DDIM, tot * (1.0f / 8388608.0f));
  }
}

// ---------------------------------------------------------------------------
// Fallback tier 2: mono (round-1 structure, proven semantics)
// ---------------------------------------------------------------------------
__global__ __launch_bounds__(NT, 2)
void vq_mono(const float* __restrict__ latent, const float* __restrict__ weight,
             const float* __restrict__ wnorm, float* __restrict__ out) {
  __shared__ __align__(16) float As[BD][BN];
  __shared__ __align__(16) float Ws[BD][WSP];
  __shared__ int   sIdx[BN];
  __shared__ float sRed[4];

  const int tid = threadIdx.x;
  const int blk = blockIdx.x;
  const int tx  = tid & 15;
  const int ty  = tid >> 4;
  const int b   = blk >> 4;
  const int hw0 = (blk & 15) * BN;
  const float* lat_b = latent + (size_t)b * DDIM * HWSZ;

  float xn[4] = {0.f, 0.f, 0.f, 0.f};
  for (int dc = 0; dc < DDIM / BD; ++dc) {
    __syncthreads();
#pragma unroll
    for (int i = 0; i < 2; ++i) {
      int idx = tid + i * NT;
      int dd = idx >> 4, f4 = idx & 15;
      *(float4*)&As[dd][f4 * 4] =
          *(const float4*)(lat_b + (size_t)(dc * BD + dd) * HWSZ + hw0 + f4 * 4);
    }
    __syncthreads();
#pragma unroll 8
    for (int dd = 0; dd < BD; ++dd) {
      float4 a = *(const float4*)&As[dd][ty * 4];
      xn[0] += a.x * a.x; xn[1] += a.y * a.y;
      xn[2] += a.z * a.z; xn[3] += a.w * a.w;
    }
  }

  float best[4] = {INFINITY, INFINITY, INFINITY, INFINITY};
  int   bidx[4] = {0, 0, 0, 0};

  for (int kt = 0; kt < KCODES / BK; ++kt) {
    const int k0 = kt * BK;
    float acc[4][8];
#pragma unroll
    for (int r = 0; r < 4; ++r)
#pragma unroll
      for (int c = 0; c < 8; ++c) acc[r][c] = 0.f;

    for (int dc = 0; dc < DDIM / BD; ++dc) {
      const int d0 = dc * BD;
      __syncthreads();
#pragma unroll
      for (int i = 0; i < 2; ++i) {
        int idx = tid + i * NT;
        int dd = idx >> 4, f4 = idx & 15;
        *(float4*)&As[dd][f4 * 4] =
            *(const float4*)(lat_b + (size_t)(d0 + dd) * HWSZ + hw0 + f4 * 4);
      }
#pragma unroll
      for (int i = 0; i < 4; ++i) {
        int idx = tid + i * NT;
        int kl = idx >> 3, df = idx & 7;
        float4 v = *(const float4*)(weight + (size_t)(k0 + kl) * DDIM + d0 + df * 4);
        Ws[df * 4 + 0][kl] = v.x;
        Ws[df * 4 + 1][kl] = v.y;
        Ws[df * 4 + 2][kl] = v.z;
        Ws[df * 4 + 3][kl] = v.w;
      }
      __syncthreads();

#pragma unroll 8
      for (int dd = 0; dd < BD; ++dd) {
        float4 a  = *(const float4*)&As[dd][ty * 4];
        float4 w0 = *(const float4*)&Ws[dd][tx * 4];
        float4 w1 = *(const float4*)&Ws[dd][64 + tx * 4];
        float av[4] = {a.x, a.y, a.z, a.w};
        float wv[8] = {w0.x, w0.y, w0.z, w0.w, w1.x, w1.y, w1.z, w1.w};
#pragma unroll
        for (int r = 0; r < 4; ++r)
#pragma unroll
          for (int c = 0; c < 8; ++c)
            acc[r][c] += av[r] * wv[c];
      }
    }

#pragma unroll
    for (int c = 0; c < 8; ++c) {
      const int kg = k0 + ((c < 4) ? (tx * 4 + c) : (64 + tx * 4 + (c - 4)));
      const float wn = wnorm[kg];
#pragma unroll
      for (int r = 0; r < 4; ++r) {
        float dist = (xn[r] + wn) - 2.0f * acc[r][c];
        if (dist < best[r] || (dist == best[r] && kg < bidx[r])) {
          best[r] = dist; bidx[r] = kg;
        }
      }
    }
  }

#pragma unroll
  for (int j = 0; j < 4; ++j) {
    float bd = best[j];
    int   bi = bidx[j];
#pragma unroll
    for (int off = 1; off < 16; off <<= 1) {
      float od = __shfl_xor(bd, off);
      int   oi = __shfl_xor(bi, off);
      if (od < bd || (od == bd && oi < bi)) { bd = od; bi = oi; }
    }
    if (tx == 0) sIdx[ty * 4 + j] = bi;
  }
  __syncthreads();

  const int hwl = tid & 63;
  const int wv  = tid >> 6;
  const int ksel = sIdx[hwl];
  const float* wrow = weight + (size_t)ksel * DDIM;
  float lsum = 0.f;
#pragma unroll 4
  for (int it = 0; it < 64; ++it) {
    int d = it * 4 + wv;
    size_t off = (size_t)d * HWSZ + hw0 + hwl;
    float x = lat_b[off];
    float qv = wrow[d];
    out[(size_t)b * DDIM * HWSZ + off] = qv;
    float df = qv - x;
    lsum += df * df;
  }
#pragma unroll
  for (int off = 1; off < 64; off <<= 1) lsum += __shfl_xor(lsum, off);
  if ((tid & 63) == 0) sRed[tid >> 6] = lsum;
  __syncthreads();
  if (tid == 0) {
    float t = sRed[0] + sRed[1] + sRed[2] + sRed[3];
    atomicAdd(out + (size_t)NROWS * DDIM, t * (1.0f / ((float)NROWS * (float)DDIM)));
  }
}

// ---------------------------------------------------------------------------
extern "C" void kernel_launch(void* const* d_in, const int* in_sizes, int n_in,
                              void* d_out, int out_size, void* d_ws, size_t ws_size,
                              hipStream_t stream) {
  const float* latent = (const float*)d_in[0];   // (32,256,32,32) f32
  const float* weight = (const float*)d_in[1];   // (1024,256)     f32
  float* out   = (float*)d_out;                  // 8388608 + 1 (loss)
  char*  ws    = (char*)d_ws;
  float* wnorm = (float*)(ws + WS_WNORM);

  vq_wnorm<<<KCODES / 4, 256, 0, stream>>>(weight, wnorm, out + (size_t)NROWS * DDIM);

  if (ws_size >= (size_t)WS_NEED_MFMA) {
    vq_prep <<<KCODES / 8, 256, 0, stream>>>(weight, ws);
    vq_mfma3<<<1024, 512, 0, stream>>>(latent, weight, ws, out);
    vq_fixc <<< 512, 256, 0, stream>>>(latent, weight, ws, out);
  } else if (ws_size >= (size_t)WS_NEED_F32) {
    unsigned long long* keys = (unsigned long long*)(ws + WS_KEYS);
    hipMemsetAsync(ws + WS_KEYS, 0xFF, (size_t)NROWS * 8, stream);
    vq_dist<<<2048, NT, 0, stream>>>(latent, weight, wnorm, keys);
    vq_emit<<< 512, 256, 0, stream>>>(latent, weight, keys, out);
  } else {
    vq_mono<<< 512, NT, 0, stream>>>(latent, weight, wnorm, out);
  }
}

// Round 13
// 188.137 us; speedup vs baseline: 1.1944x; 1.1944x over previous
//
#include <hip/hip_runtime.h>
#include <math.h>
#include <stdint.h>

#define DDIM   256
#define HWSZ   1024
#define NROWS  32768
#define KCODES 1024
#define BN     64
#define BK     128
#define BD     32
#define NT     256
#define WSP    132
#define TAU    4.0e-4f      // flag gap threshold (3-term err ~1e-5 + grid 3e-5)

// ws layout (byte offsets)
#define WS_WNORM 0                       // float[1024]           (4 KB)
#define WS_KEYS  4096                    // u64[32768]            (256 KB)
#define WS_FLAGS 266240                  // int[32768]            (128 KB)
#define WS_WHI   397312                  // bf16 hi planes        (512 KB)
#define WS_WLO   921600                  // bf16 lo planes        (512 KB)
#define WS_NEED_MFMA 1445888
#define WS_NEED_F32  266240

typedef __attribute__((ext_vector_type(8)))  short short8;
typedef __attribute__((ext_vector_type(16))) float f32x16;

__device__ __forceinline__ uint32_t fbits(float f) { return __float_as_uint(f); }
__device__ __forceinline__ float    ubits(uint32_t u) { return __uint_as_float(u); }
__device__ __forceinline__ uint32_t bf16rne(float f) {
  uint32_t u = fbits(f);
  return (u + 0x7FFFu + ((u >> 16) & 1u)) >> 16;
}
__device__ __forceinline__ uint32_t flipbits(float d) {
  uint32_t b = fbits(d);
  return (b & 0x80000000u) ? ~b : (b | 0x80000000u);
}
__device__ __forceinline__ float unflip(uint32_t x) {
  return ubits((x & 0x80000000u) ? (x & 0x7FFFFFFFu) : ~x);
}
__device__ __forceinline__ unsigned long long umin64(unsigned long long a, unsigned long long b) { return a < b ? a : b; }
__device__ __forceinline__ unsigned long long umax64(unsigned long long a, unsigned long long b) { return a > b ? a : b; }

// ---------------------------------------------------------------------------
// k1: per-code squared norms + zero the loss slot (proven, verbatim)
// ---------------------------------------------------------------------------
__global__ __launch_bounds__(256)
void vq_wnorm(const float* __restrict__ weight, float* __restrict__ wnorm,
              float* __restrict__ loss_slot) {
  const int tid  = threadIdx.x;
  const int lane = tid & 63;
  const int code = blockIdx.x * 4 + (tid >> 6);
  float4 v = *(const float4*)(weight + (size_t)code * DDIM + lane * 4);
  float s = v.x * v.x + v.y * v.y + v.z * v.z + v.w * v.w;
#pragma unroll
  for (int off = 1; off < 64; off <<= 1) s += __shfl_xor(s, off);
  if (lane == 0) wnorm[code] = s;
  if (blockIdx.x == 0 && tid == 0) *loss_slot = 0.0f;
}

// ---------------------------------------------------------------------------
// k1b: codebook -> bf16 hi/lo planes (proven layout, verbatim)
// plane per 16-dim chunk: [2 oct][1024 code][8 bf16] = 32 KB
// ---------------------------------------------------------------------------
__global__ __launch_bounds__(256)
void vq_prep(const float* __restrict__ weight, char* __restrict__ ws) {
  const int t    = threadIdx.x;
  const int code = blockIdx.x * 8 + (t >> 5);
  const int l32  = t & 31;
  const int d0   = l32 * 8;
  const int ch   = l32 >> 1;
  const int slot = l32 & 1;
  const float* wr = weight + (size_t)code * DDIM + d0;
  float4 f0 = *(const float4*)(wr);
  float4 f1 = *(const float4*)(wr + 4);
  float x[8] = {f0.x, f0.y, f0.z, f0.w, f1.x, f1.y, f1.z, f1.w};
  uint32_t hp[4], lp[4];
#pragma unroll
  for (int j = 0; j < 4; ++j) {
    float a = x[2*j], b = x[2*j+1];
    uint32_t ha = bf16rne(a), hb = bf16rne(b);
    float la = a - ubits(ha << 16);
    float lb = b - ubits(hb << 16);
    hp[j] = ha | (hb << 16);
    lp[j] = bf16rne(la) | (bf16rne(lb) << 16);
  }
  const size_t off = (size_t)ch * 32768 + (size_t)slot * 16384 + (size_t)code * 16;
  *(uint4*)(ws + WS_WHI + off) = make_uint4(hp[0], hp[1], hp[2], hp[3]);
  *(uint4*)(ws + WS_WLO + off) = make_uint4(lp[0], lp[1], lp[2], lp[3]);
}

// ---------------------------------------------------------------------------
// k2: 3-term split-bf16 MFMA argmin (round-11 barrier-free loop, verbatim),
// verify section REMOVED (layout proven, gap-flag kept), epilogue gathers
// code rows through LDS (coalesced) instead of per-lane scattered reads.
// ---------------------------------------------------------------------------
__global__ __launch_bounds__(512)
void vq_mfma3(const float* __restrict__ latent, const float* __restrict__ weight,
              char* __restrict__ ws, float* __restrict__ out) {
  // SMEM reuse: phase 1 = A-tiles (AH 16 KB @0, AL 16 KB @16384);
  //             phase 2 (epilogue) = qs[32][258] f32 (33 KB) over the same bytes
  __shared__ __align__(16) char SMEM[33024];
  __shared__ ulonglong2 cand[32][8];                // 4 KB
  __shared__ unsigned long long sM1[32];
  __shared__ int sGap[32];
  __shared__ float sRed[8];

  typedef short (*Atile)[2][32][8];
  Atile AH = (Atile)(SMEM);
  Atile AL = (Atile)(SMEM + 16384);
  float* qs = (float*)SMEM;                         // [32][258] padded

  const int tid  = threadIdx.x;
  const int l    = tid & 63;
  const int w    = tid >> 6;
  const int ln31 = l & 31;
  const int half = l >> 5;
  const int b    = blockIdx.x >> 5;
  const int hw0  = (blockIdx.x & 31) * 32;
  const float* lat_b = latent + (size_t)b * (DDIM * HWSZ);
  const char* whi = ws + WS_WHI;
  const char* wlo = ws + WS_WLO;
  const float* wnorm = (const float*)(ws + WS_WNORM);

  f32x16 acc[4];
#pragma unroll
  for (int cg = 0; cg < 4; ++cg) acc[cg] = (f32x16)0.0f;

  // ---- stage ALL of A once: thread (arow, adim) covers 16 chunks ----
  {
    const int arow = tid & 31;
    const int adim = tid >> 5;          // 0..15
#pragma unroll 4
    for (int ch = 0; ch < 16; ++ch) {
      float x = lat_b[(size_t)(ch * 16 + adim) * HWSZ + hw0 + arow];
      uint32_t h = bf16rne(x);
      float lo = x - ubits(h << 16);
      AH[ch][adim >> 3][arow][adim & 7] = (short)h;
      AL[ch][adim >> 3][arow][adim & 7] = (short)bf16rne(lo);
    }
  }
  __syncthreads();   // the ONLY barrier before the fold

  // ---- barrier-free MFMA loop (round-11 verbatim) ----
#pragma unroll 1
  for (int ch = 0; ch < 16; ++ch) {
    short8 ah = *(const short8*)&AH[ch][half][ln31][0];
    short8 al = *(const short8*)&AL[ch][half][ln31][0];
#pragma unroll
    for (int cg = 0; cg < 4; ++cg) {
      const int code = w * 128 + cg * 32 + ln31;
      const size_t boff = (size_t)ch * 32768 + (size_t)half * 16384 + (size_t)code * 16;
      short8 bh = *(const short8*)(whi + boff);   // L2-resident, coalesced
      short8 bl = *(const short8*)(wlo + boff);
      acc[cg] = __builtin_amdgcn_mfma_f32_32x32x16_bf16(ah, bh, acc[cg], 0, 0, 0);
      acc[cg] = __builtin_amdgcn_mfma_f32_32x32x16_bf16(al, bh, acc[cg], 0, 0, 0);
      acc[cg] = __builtin_amdgcn_mfma_f32_32x32x16_bf16(ah, bl, acc[cg], 0, 0, 0);
    }
  }

  // ---- fold: per-row best/second-best over this wave's 128 codes ----
  float wnv[4];
#pragma unroll
  for (int cg = 0; cg < 4; ++cg) wnv[cg] = wnorm[w * 128 + cg * 32 + ln31];

#pragma unroll
  for (int reg = 0; reg < 16; ++reg) {
    unsigned long long kk[4];
#pragma unroll
    for (int cg = 0; cg < 4; ++cg) {
      const int code = w * 128 + cg * 32 + ln31;
      float dk = fmaf(-2.0f, acc[cg][reg], wnv[cg]);   // xn dropped: gap-flag covers
      kk[cg] = (((unsigned long long)flipbits(dk)) << 32) | (unsigned long long)(uint32_t)code;
    }
    unsigned long long a = umin64(kk[0], kk[1]), bb = umax64(kk[0], kk[1]);
    unsigned long long c = umin64(kk[2], kk[3]), e  = umax64(kk[2], kk[3]);
    unsigned long long m1 = umin64(a, c);
    unsigned long long m2 = umin64(umin64(bb, e), umax64(a, c));
#pragma unroll
    for (int s = 1; s <= 16; s <<= 1) {
      unsigned long long om1 = __shfl_xor(m1, s);
      unsigned long long om2 = __shfl_xor(m2, s);
      unsigned long long nm2 = umin64(umin64(m2, om2), umax64(m1, om1));
      m1 = umin64(m1, om1);
      m2 = nm2;
    }
    if (ln31 == 0) {
      const int row = (reg & 3) + 8 * (reg >> 2) + 4 * half;   // verified C/D map
      cand[row][w] = make_ulonglong2(m1, m2);
    }
  }
  __syncthreads();

  // ---- merge across waves; keys plain store (single writer per row) ----
  unsigned long long* keys = (unsigned long long*)(ws + WS_KEYS);
  if (tid < 256) {
    const int row = tid >> 3, ww = tid & 7;
    ulonglong2 cc = cand[row][ww];
    unsigned long long m1 = cc.x, m2 = cc.y;
#pragma unroll
    for (int s = 1; s <= 4; s <<= 1) {
      unsigned long long om1 = __shfl_xor(m1, s);
      unsigned long long om2 = __shfl_xor(m2, s);
      unsigned long long nm2 = umin64(umin64(m2, om2), umax64(m1, om1));
      m1 = umin64(m1, om1);
      m2 = nm2;
    }
    if (ww == 0) {
      keys[blockIdx.x * 32 + row] = m1;
      float d1 = unflip((uint32_t)(m1 >> 32));
      float d2 = unflip((uint32_t)(m2 >> 32));
      sGap[row] = (d2 - d1 < TAU) ? 1 : 0;
      sM1[row]  = m1;
    }
  }
  __syncthreads();   // sM1/sGap visible; A-tiles dead from here

  if (tid < 32)
    ((int*)(ws + WS_FLAGS))[blockIdx.x * 32 + tid] = sGap[tid];

  // ---- stage gathered code rows into LDS (coalesced global reads) ----
  {
    const int r  = tid >> 4;                 // 32 rows x 16 threads
    const int d0 = (tid & 15) * 16;
    const int ec = (int)(sM1[r] & 0x3FFull);
    const float* wr = weight + (size_t)ec * DDIM + d0;
    float* dst = qs + r * 258 + d0;          // stride 258: 2-way bank reads (free)
#pragma unroll
    for (int j = 0; j < 4; ++j) {
      float4 v = *(const float4*)(wr + j * 4);
      *(float2*)(dst + j * 4)     = make_float2(v.x, v.y);
      *(float2*)(dst + j * 4 + 2) = make_float2(v.z, v.w);
    }
  }
  __syncthreads();

  // ---- fused epilogue: transposed write + commitment loss (all coalesced) ----
  {
    const int er = tid & 31;
    const int eg = tid >> 5;
    float* out_b = out + (size_t)b * (DDIM * HWSZ);
    float ls = 0.f;
#pragma unroll
    for (int i = 0; i < 16; ++i) {
      const int d = i * 16 + eg;
      const size_t off = (size_t)d * HWSZ + hw0 + er;
      float x  = lat_b[off];
      float qv = qs[er * 258 + d];
      out_b[off] = qv;
      float e = qv - x;
      ls += e * e;
    }
#pragma unroll
    for (int s = 1; s < 64; s <<= 1) ls += __shfl_xor(ls, s);
    if (l == 0) sRed[w] = ls;
  }
  __syncthreads();
  if (tid == 0) {
    float t = 0.f;
#pragma unroll
    for (int i = 0; i < 8; ++i) t += sRed[i];
    atomicAdd(out + (size_t)NROWS * DDIM, t * (1.0f / 8388608.0f));
  }
}

// ---------------------------------------------------------------------------
// k2b: exact coarse-grid re-argmin for flagged rows (round-6 math verbatim);
// rewrites the output row and patches the loss delta.
// ---------------------------------------------------------------------------
__global__ __launch_bounds__(256)
void vq_fixc(const float* __restrict__ latent, const float* __restrict__ weight,
             char* __restrict__ ws, float* __restrict__ out) {
  __shared__ float xs[256];
  __shared__ float bd[4];
  __shared__ int   bix[4];
  __shared__ int   sNew;
  __shared__ float sDl[4];
  const int t = threadIdx.x;
  const int* flags = (const int*)(ws + WS_FLAGS);
  const float* wnorm = (const float*)(ws + WS_WNORM);
  const unsigned long long* keys = (const unsigned long long*)(ws + WS_KEYS);

  for (int rloc = 0; rloc < 64; ++rloc) {
    const int grow = blockIdx.x * 64 + rloc;
    if (!flags[grow]) continue;                      // uniform per block
    const int b = grow >> 10, hw = grow & 1023;
    __syncthreads();
    xs[t] = latent[(size_t)b * (DDIM * HWSZ) + (size_t)t * HWSZ + hw];
    __syncthreads();
    float xnv = 0.f;
    const float4* x4 = (const float4*)xs;
#pragma unroll 16
    for (int k = 0; k < 64; ++k) {
      float4 xq = x4[k];
      xnv += xq.x * xq.x; xnv += xq.y * xq.y;
      xnv += xq.z * xq.z; xnv += xq.w * xq.w;
    }
    float best = INFINITY; int bi = 0;
    for (int j = 0; j < 4; ++j) {
      const int c = 256 * j + t;
      const float4* w4 = (const float4*)(weight + (size_t)c * DDIM);
      float dot = 0.f;
#pragma unroll 16
      for (int k = 0; k < 64; ++k) {
        float4 wv = w4[k];
        dot = fmaf(xs[4*k  ], wv.x, dot);
        dot = fmaf(xs[4*k+1], wv.y, dot);
        dot = fmaf(xs[4*k+2], wv.z, dot);
        dot = fmaf(xs[4*k+3], wv.w, dot);
      }
      float dist = (xnv + wnorm[c]) - 2.0f * dot;    // coarse grid, verbatim
      if (dist < best || (dist == best && c < bi)) { best = dist; bi = c; }
    }
#pragma unroll
    for (int s = 1; s <= 32; s <<= 1) {
      float od = __shfl_xor(best, s);
      int   oi = __shfl_xor(bi, s);
      if (od < best || (od == best && oi < bi)) { best = od; bi = oi; }
    }
    if ((t & 63) == 0) { bd[t >> 6] = best; bix[t >> 6] = bi; }
    __syncthreads();
    if (t == 0) {
      float fb = bd[0]; int fbi = bix[0];
#pragma unroll
      for (int ww = 1; ww < 4; ++ww)
        if (bd[ww] < fb || (bd[ww] == fb && bix[ww] < fbi)) { fb = bd[ww]; fbi = bix[ww]; }
      sNew = fbi;
    }
    __syncthreads();
    const int newc = sNew;
    const int oldc = (int)(keys[grow] & 0x3FFull);
    const float x  = xs[t];
    const float qn = weight[(size_t)newc * DDIM + t];
    const float qo = weight[(size_t)oldc * DDIM + t];
    out[(size_t)b * (DDIM * HWSZ) + (size_t)t * HWSZ + hw] = qn;
    float dl = (qn - x) * (qn - x) - (qo - x) * (qo - x);
#pragma unroll
    for (int s = 1; s < 64; s <<= 1) dl += __shfl_xor(dl, s);
    if ((t & 63) == 0) sDl[t >> 6] = dl;
    __syncthreads();
    if (t == 0)
      atomicAdd(out + (size_t)NROWS * DDIM,
                (sDl[0] + sDl[1] + sDl[2] + sDl[3]) * (1.0f / 8388608.0f));
    __syncthreads();
  }
}

// ---------------------------------------------------------------------------
// Fallback tier 1: round-6 proven f32 kernel (verbatim)
// ---------------------------------------------------------------------------
__global__ __launch_bounds__(NT, 4)
void vq_dist(const float* __restrict__ latent, const float* __restrict__ weight,
             const float* __restrict__ wnorm,
             unsigned long long* __restrict__ keys) {
  __shared__ __align__(16) float As[BD][BN];
  __shared__ __align__(16) float Ws[BD][WSP];

  const int tid = threadIdx.x;
  const int tx  = tid & 15;
  const int ty  = tid >> 4;
  const int rb  = blockIdx.x >> 2;
  const int q   = blockIdx.x & 3;
  const int b   = rb >> 4;
  const int hw0 = (rb & 15) * BN;
  const float* lat_b = latent + (size_t)b * DDIM * HWSZ;

  float xn[4] = {0.f, 0.f, 0.f, 0.f};
  for (int dc = 0; dc < DDIM / BD; ++dc) {
    __syncthreads();
#pragma unroll
    for (int i = 0; i < 2; ++i) {
      int idx = tid + i * NT;
      int dd = idx >> 4, f4 = idx & 15;
      *(float4*)&As[dd][f4 * 4] =
          *(const float4*)(lat_b + (size_t)(dc * BD + dd) * HWSZ + hw0 + f4 * 4);
    }
    __syncthreads();
#pragma unroll 8
    for (int dd = 0; dd < BD; ++dd) {
      float4 a = *(const float4*)&As[dd][ty * 4];
      xn[0] += a.x * a.x; xn[1] += a.y * a.y;
      xn[2] += a.z * a.z; xn[3] += a.w * a.w;
    }
  }

  float best[4] = {INFINITY, INFINITY, INFINITY, INFINITY};
  int   bidx[4] = {0, 0, 0, 0};

  for (int kt = 0; kt < 2; ++kt) {
    const int k0 = q * 256 + kt * BK;
    float acc[4][8];
#pragma unroll
    for (int r = 0; r < 4; ++r)
#pragma unroll
      for (int c = 0; c < 8; ++c) acc[r][c] = 0.f;

    for (int dc = 0; dc < DDIM / BD; ++dc) {
      const int d0 = dc * BD;
      __syncthreads();
#pragma unroll
      for (int i = 0; i < 2; ++i) {
        int idx = tid + i * NT;
        int dd = idx >> 4, f4 = idx & 15;
        *(float4*)&As[dd][f4 * 4] =
            *(const float4*)(lat_b + (size_t)(d0 + dd) * HWSZ + hw0 + f4 * 4);
      }
#pragma unroll
      for (int i = 0; i < 4; ++i) {
        int idx = tid + i * NT;
        int kl = idx >> 3, df = idx & 7;
        float4 v = *(const float4*)(weight + (size_t)(k0 + kl) * DDIM + d0 + df * 4);
        Ws[df * 4 + 0][kl] = v.x;
        Ws[df * 4 + 1][kl] = v.y;
        Ws[df * 4 + 2][kl] = v.z;
        Ws[df * 4 + 3][kl] = v.w;
      }
      __syncthreads();

#pragma unroll 8
      for (int dd = 0; dd < BD; ++dd) {
        float4 a  = *(const float4*)&As[dd][ty * 4];
        float4 w0 = *(const float4*)&Ws[dd][tx * 4];
        float4 w1 = *(const float4*)&Ws[dd][64 + tx * 4];
        float av[4] = {a.x, a.y, a.z, a.w};
        float wv[8] = {w0.x, w0.y, w0.z, w0.w, w1.x, w1.y, w1.z, w1.w};
#pragma unroll
        for (int r = 0; r < 4; ++r)
#pragma unroll
          for (int c = 0; c < 8; ++c)
            acc[r][c] += av[r] * wv[c];
      }
    }

#pragma unroll
    for (int c = 0; c < 8; ++c) {
      const int kg = k0 + ((c < 4) ? (tx * 4 + c) : (64 + tx * 4 + (c - 4)));
      const float wn = wnorm[kg];
#pragma unroll
      for (int r = 0; r < 4; ++r) {
        float dist = (xn[r] + wn) - 2.0f * acc[r][c];
        if (dist < best[r] || (dist == best[r] && kg < bidx[r])) {
          best[r] = dist; bidx[r] = kg;
        }
      }
    }
  }

#pragma unroll
  for (int j = 0; j < 4; ++j) {
    float bd = best[j];
    int   bi = bidx[j];
#pragma unroll
    for (int off = 1; off < 16; off <<= 1) {
      float od = __shfl_xor(bd, off);
      int   oi = __shfl_xor(bi, off);
      if (od < bd || (od == bd && oi < bi)) { bd = od; bi = oi; }
    }
    if (tx == 0) {
      unsigned long long key =
          (((unsigned long long)flipbits(bd)) << 32) | (unsigned long long)(uint32_t)bi;
      atomicMin(&keys[rb * 64 + ty * 4 + j], key);
    }
  }
}

// ---------------------------------------------------------------------------
// Fallback tier 1 epilogue (proven vq_emit)
// ---------------------------------------------------------------------------
__global__ __launch_bounds__(256)
void vq_emit(const float* __restrict__ latent, const float* __restrict__ weight,
             const unsigned long long* __restrict__ keys, float* __restrict__ out) {
  __shared__ int   sIdx[64];
  __shared__ float sRed[4];
  const int t   = threadIdx.x;
  const int blk = blockIdx.x;
  const int b   = blk >> 4;
  const int hw0 = (blk & 15) * 64;
  if (t < 64) sIdx[t] = (int)(keys[blk * 64 + t] & 0x3FFull);
  __syncthreads();

  const int hw4  = (t & 15) * 4;
  const int dgrp = t >> 4;
  const float* lat_b = latent + (size_t)b * DDIM * HWSZ;
  float* out_b = out + (size_t)b * DDIM * HWSZ;
  const float* w0 = weight + (size_t)sIdx[hw4 + 0] * DDIM;
  const float* w1 = weight + (size_t)sIdx[hw4 + 1] * DDIM;
  const float* w2 = weight + (size_t)sIdx[hw4 + 2] * DDIM;
  const float* w3 = weight + (size_t)sIdx[hw4 + 3] * DDIM;
  float lsum = 0.f;
#pragma unroll
  for (int it = 0; it < 16; ++it) {
    const int d = it * 16 + dgrp;
    float4 xv = *(const float4*)(lat_b + (size_t)d * HWSZ + hw0 + hw4);
    float q0 = w0[d], q1 = w1[d], q2 = w2[d], q3 = w3[d];
    *(float4*)(out_b + (size_t)d * HWSZ + hw0 + hw4) = make_float4(q0, q1, q2, q3);
    float e0 = q0 - xv.x, e1 = q1 - xv.y, e2 = q2 - xv.z, e3 = q3 - xv.w;
    lsum += e0 * e0 + e1 * e1 + e2 * e2 + e3 * e3;
  }
#pragma unroll
  for (int s = 1; s < 64; s <<= 1) lsum += __shfl_xor(lsum, s);
  if ((t & 63) == 0) sRed[t >> 6] = lsum;
  __syncthreads();
  if (t == 0) {
    float tot = sRed[0] + sRed[1] + sRed[2] + sRed[3];
    atomicAdd(out + (size_t)NROWS * DDIM, tot * (1.0f / 8388608.0f));
  }
}

// ---------------------------------------------------------------------------
// Fallback tier 2: mono (round-1 structure, proven semantics)
// ---------------------------------------------------------------------------
__global__ __launch_bounds__(NT, 2)
void vq_mono(const float* __restrict__ latent, const float* __restrict__ weight,
             const float* __restrict__ wnorm, float* __restrict__ out) {
  __shared__ __align__(16) float As[BD][BN];
  __shared__ __align__(16) float Ws[BD][WSP];
  __shared__ int   sIdx[BN];
  __shared__ float sRed[4];

  const int tid = threadIdx.x;
  const int blk = blockIdx.x;
  const int tx  = tid & 15;
  const int ty  = tid >> 4;
  const int b   = blk >> 4;
  const int hw0 = (blk & 15) * BN;
  const float* lat_b = latent + (size_t)b * DDIM * HWSZ;

  float xn[4] = {0.f, 0.f, 0.f, 0.f};
  for (int dc = 0; dc < DDIM / BD; ++dc) {
    __syncthreads();
#pragma unroll
    for (int i = 0; i < 2; ++i) {
      int idx = tid + i * NT;
      int dd = idx >> 4, f4 = idx & 15;
      *(float4*)&As[dd][f4 * 4] =
          *(const float4*)(lat_b + (size_t)(dc * BD + dd) * HWSZ + hw0 + f4 * 4);
    }
    __syncthreads();
#pragma unroll 8
    for (int dd = 0; dd < BD; ++dd) {
      float4 a = *(const float4*)&As[dd][ty * 4];
      xn[0] += a.x * a.x; xn[1] += a.y * a.y;
      xn[2] += a.z * a.z; xn[3] += a.w * a.w;
    }
  }

  float best[4] = {INFINITY, INFINITY, INFINITY, INFINITY};
  int   bidx[4] = {0, 0, 0, 0};

  for (int kt = 0; kt < KCODES / BK; ++kt) {
    const int k0 = kt * BK;
    float acc[4][8];
#pragma unroll
    for (int r = 0; r < 4; ++r)
#pragma unroll
      for (int c = 0; c < 8; ++c) acc[r][c] = 0.f;

    for (int dc = 0; dc < DDIM / BD; ++dc) {
      const int d0 = dc * BD;
      __syncthreads();
#pragma unroll
      for (int i = 0; i < 2; ++i) {
        int idx = tid + i * NT;
        int dd = idx >> 4, f4 = idx & 15;
        *(float4*)&As[dd][f4 * 4] =
            *(const float4*)(lat_b + (size_t)(d0 + dd) * HWSZ + hw0 + f4 * 4);
      }
#pragma unroll
      for (int i = 0; i < 4; ++i) {
        int idx = tid + i * NT;
        int kl = idx >> 3, df = idx & 7;
        float4 v = *(const float4*)(weight + (size_t)(k0 + kl) * DDIM + d0 + df * 4);
        Ws[df * 4 + 0][kl] = v.x;
        Ws[df * 4 + 1][kl] = v.y;
        Ws[df * 4 + 2][kl] = v.z;
        Ws[df * 4 + 3][kl] = v.w;
      }
      __syncthreads();

#pragma unroll 8
      for (int dd = 0; dd < BD; ++dd) {
        float4 a  = *(const float4*)&As[dd][ty * 4];
        float4 w0 = *(const float4*)&Ws[dd][tx * 4];
        float4 w1 = *(const float4*)&Ws[dd][64 + tx * 4];
        float av[4] = {a.x, a.y, a.z, a.w};
        float wv[8] = {w0.x, w0.y, w0.z, w0.w, w1.x, w1.y, w1.z, w1.w};
#pragma unroll
        for (int r = 0; r < 4; ++r)
#pragma unroll
          for (int c = 0; c < 8; ++c)
            acc[r][c] += av[r] * wv[c];
      }
    }

#pragma unroll
    for (int c = 0; c < 8; ++c) {
      const int kg = k0 + ((c < 4) ? (tx * 4 + c) : (64 + tx * 4 + (c - 4)));
      const float wn = wnorm[kg];
#pragma unroll
      for (int r = 0; r < 4; ++r) {
        float dist = (xn[r] + wn) - 2.0f * acc[r][c];
        if (dist < best[r] || (dist == best[r] && kg < bidx[r])) {
          best[r] = dist; bidx[r] = kg;
        }
      }
    }
  }

#pragma unroll
  for (int j = 0; j < 4; ++j) {
    float bd = best[j];
    int   bi = bidx[j];
#pragma unroll
    for (int off = 1; off < 16; off <<= 1) {
      float od = __shfl_xor(bd, off);
      int   oi = __shfl_xor(bi, off);
      if (od < bd || (od == bd && oi < bi)) { bd = od; bi = oi; }
    }
    if (tx == 0) sIdx[ty * 4 + j] = bi;
  }
  __syncthreads();

  const int hwl = tid & 63;
  const int wv  = tid >> 6;
  const int ksel = sIdx[hwl];
  const float* wrow = weight + (size_t)ksel * DDIM;
  float lsum = 0.f;
#pragma unroll 4
  for (int it = 0; it < 64; ++it) {
    int d = it * 4 + wv;
    size_t off = (size_t)d * HWSZ + hw0 + hwl;
    float x = lat_b[off];
    float qv = wrow[d];
    out[(size_t)b * DDIM * HWSZ + off] = qv;
    float df = qv - x;
    lsum += df * df;
  }
#pragma unroll
  for (int off = 1; off < 64; off <<= 1) lsum += __shfl_xor(lsum, off);
  if ((tid & 63) == 0) sRed[tid >> 6] = lsum;
  __syncthreads();
  if (tid == 0) {
    float t = sRed[0] + sRed[1] + sRed[2] + sRed[3];
    atomicAdd(out + (size_t)NROWS * DDIM, t * (1.0f / ((float)NROWS * (float)DDIM)));
  }
}

// ---------------------------------------------------------------------------
extern "C" void kernel_launch(void* const* d_in, const int* in_sizes, int n_in,
                              void* d_out, int out_size, void* d_ws, size_t ws_size,
                              hipStream_t stream) {
  const float* latent = (const float*)d_in[0];   // (32,256,32,32) f32
  const float* weight = (const float*)d_in[1];   // (1024,256)     f32
  float* out   = (float*)d_out;                  // 8388608 + 1 (loss)
  char*  ws    = (char*)d_ws;
  float* wnorm = (float*)(ws + WS_WNORM);

  vq_wnorm<<<KCODES / 4, 256, 0, stream>>>(weight, wnorm, out + (size_t)NROWS * DDIM);

  if (ws_size >= (size_t)WS_NEED_MFMA) {
    vq_prep <<<KCODES / 8, 256, 0, stream>>>(weight, ws);
    vq_mfma3<<<1024, 512, 0, stream>>>(latent, weight, ws, out);
    vq_fixc <<< 512, 256, 0, stream>>>(latent, weight, ws, out);
  } else if (ws_size >= (size_t)WS_NEED_F32) {
    unsigned long long* keys = (unsigned long long*)(ws + WS_KEYS);
    hipMemsetAsync(ws + WS_KEYS, 0xFF, (size_t)NROWS * 8, stream);
    vq_dist<<<2048, NT, 0, stream>>>(latent, weight, wnorm, keys);
    vq_emit<<< 512, 256, 0, stream>>>(latent, weight, keys, out);
  } else {
    vq_mono<<< 512, NT, 0, stream>>>(latent, weight, wnorm, out);
  }
}